// Round 1
// baseline (8580.412 us; speedup 1.0000x reference)
//
#include <hip/hip_runtime.h>
#include <hip/hip_bf16.h>
#include <cstdint>

#define B_   16
#define C_   256
#define N_   8192
#define CN_  128
#define CL_  64
#define MID_ 128

// ---------------------------------------------------------------------------
// K1: att[b,n,l] = sum_c w_att[c] * curves[b,c,n,l]
// grid 16*32, block 256. Each block: 4 n-rows (nc*4..nc*4+3), all l, all c.
// ---------------------------------------------------------------------------
__global__ __launch_bounds__(256) void k_att(const float* __restrict__ curves,
                                             const float* __restrict__ w_att,
                                             float* __restrict__ att) {
  const int blk = blockIdx.x;
  const int b = blk >> 5, nc = blk & 31;
  const int tid = threadIdx.x;
  // element offset within [n,l] plane: nc*256 + tid  (4 rows x 64 l)
  const float* cb = curves + (size_t)b * C_ * CN_ * CL_ + nc * 256 + tid;
  float a0 = 0.f, a1 = 0.f, a2 = 0.f, a3 = 0.f;
  for (int c0 = 0; c0 < C_; c0 += 4) {
    a0 = fmaf(w_att[c0 + 0], cb[(size_t)(c0 + 0) * 8192], a0);
    a1 = fmaf(w_att[c0 + 1], cb[(size_t)(c0 + 1) * 8192], a1);
    a2 = fmaf(w_att[c0 + 2], cb[(size_t)(c0 + 2) * 8192], a2);
    a3 = fmaf(w_att[c0 + 3], cb[(size_t)(c0 + 3) * 8192], a3);
  }
  att[b * 8192 + nc * 256 + tid] = (a0 + a1) + (a2 + a3);
}

// ---------------------------------------------------------------------------
// K2: softmax over l (inter) and over n (intra) of att[b,:,:]
// grid 16, block 256
// ---------------------------------------------------------------------------
__global__ __launch_bounds__(256) void k_softmax(const float* __restrict__ att,
                                                 float* __restrict__ smi,
                                                 float* __restrict__ sma) {
  __shared__ float T[CN_ * CL_];
  __shared__ float rmax[CN_], rrcp[CN_], cmax[CL_], crcp[CL_];
  const int b = blockIdx.x;
  const int tid = threadIdx.x;
  for (int idx = tid; idx < CN_ * CL_; idx += 256) T[idx] = att[b * 8192 + idx];
  __syncthreads();
  if (tid < 128) {            // row n = tid: softmax over l
    const int n = tid;
    float mx = -1e30f;
    for (int l = 0; l < CL_; ++l) mx = fmaxf(mx, T[n * 64 + l]);
    float s = 0.f;
    for (int l = 0; l < CL_; ++l) s += __expf(T[n * 64 + l] - mx);
    rmax[n] = mx; rrcp[n] = 1.f / s;
  } else if (tid < 192) {     // col l: softmax over n
    const int l = tid - 128;
    float mx = -1e30f;
    for (int n = 0; n < CN_; ++n) mx = fmaxf(mx, T[n * 64 + l]);
    float s = 0.f;
    for (int n = 0; n < CN_; ++n) s += __expf(T[n * 64 + l] - mx);
    cmax[l] = mx; crcp[l] = 1.f / s;
  }
  __syncthreads();
  for (int idx = tid; idx < CN_ * CL_; idx += 256) {
    const int n = idx >> 6, l = idx & 63;
    const float v = T[idx];
    smi[b * 8192 + idx] = __expf(v - rmax[n]) * rrcp[n];
    sma[b * 8192 + idx] = __expf(v - cmax[l]) * crcp[l];
  }
}

// ---------------------------------------------------------------------------
// K3: cinter[b,c,n] = sum_l curves[b,c,n,l]*smi[b,n,l]
//     cintra[b,c,l] = sum_n curves[b,c,n,l]*sma[b,n,l]
// grid 16*256 (one block per (b,c)), block 256
// ---------------------------------------------------------------------------
__global__ __launch_bounds__(256) void k_agg(const float* __restrict__ curves,
                                             const float* __restrict__ smi,
                                             const float* __restrict__ sma,
                                             float* __restrict__ cinter,
                                             float* __restrict__ cintra) {
  __shared__ float P[CN_ * CL_];
  const int blk = blockIdx.x;
  const int b = blk >> 8, c = blk & 255;
  const int tid = threadIdx.x;
  const float* src = curves + (size_t)(b * 256 + c) * 8192;
  for (int i4 = tid; i4 < 2048; i4 += 256)
    *(float4*)&P[i4 * 4] = *(const float4*)&src[i4 * 4];
  __syncthreads();
  if (tid < 128) {            // n = tid, reduce over l
    const int n = tid;
    const float* sp = smi + (size_t)(b * 128 + n) * 64;
    float a[4] = {0.f, 0.f, 0.f, 0.f};
    for (int l0 = 0; l0 < 64; l0 += 4) {
      float4 pv = *(const float4*)&P[n * 64 + l0];
      float4 sv = *(const float4*)&sp[l0];
      a[0] = fmaf(pv.x, sv.x, a[0]);
      a[1] = fmaf(pv.y, sv.y, a[1]);
      a[2] = fmaf(pv.z, sv.z, a[2]);
      a[3] = fmaf(pv.w, sv.w, a[3]);
    }
    cinter[(size_t)(b * 256 + c) * 128 + n] = (a[0] + a[1]) + (a[2] + a[3]);
  } else if (tid < 192) {     // l = tid-128, reduce over n
    const int l = tid - 128;
    float a[4] = {0.f, 0.f, 0.f, 0.f};
    for (int n0 = 0; n0 < 128; n0 += 4) {
      a[0] = fmaf(P[(n0 + 0) * 64 + l], sma[(size_t)(b * 128 + n0 + 0) * 64 + l], a[0]);
      a[1] = fmaf(P[(n0 + 1) * 64 + l], sma[(size_t)(b * 128 + n0 + 1) * 64 + l], a[1]);
      a[2] = fmaf(P[(n0 + 2) * 64 + l], sma[(size_t)(b * 128 + n0 + 2) * 64 + l], a[2]);
      a[3] = fmaf(P[(n0 + 3) * 64 + l], sma[(size_t)(b * 128 + n0 + 3) * 64 + l], a[3]);
    }
    cintra[(size_t)(b * 256 + c) * 64 + l] = (a[0] + a[1]) + (a[2] + a[3]);
  }
}

// ---------------------------------------------------------------------------
// K4: a[b,m,n] = sum_c wa[m,c]*cinter[b,c,n]   (16384 outs/batch)
//     bm[b,m,l] = sum_c wb[m,c]*cintra[b,c,l]  ( 8192 outs/batch)
// grid 16*8, block 256, 12 outputs/thread
// ---------------------------------------------------------------------------
__global__ __launch_bounds__(256) void k_ab(const float* __restrict__ wa,
                                            const float* __restrict__ wb,
                                            const float* __restrict__ cinter,
                                            const float* __restrict__ cintra,
                                            float* __restrict__ amat,
                                            float* __restrict__ bmat) {
  const int blk = blockIdx.x;
  const int b = blk >> 3, part = blk & 7;
  const int tid = threadIdx.x;
  for (int k = 0; k < 12; ++k) {
    const int g = part * 3072 + k * 256 + tid;
    if (g < 16384) {
      const int m = g >> 7, n = g & 127;
      const float* w = wa + m * 256;
      const float* ci = cinter + (size_t)b * 256 * 128 + n;
      float a[4] = {0.f, 0.f, 0.f, 0.f};
      for (int c0 = 0; c0 < 256; c0 += 4) {
        float4 w4 = *(const float4*)(w + c0);
        a[0] = fmaf(w4.x, ci[(c0 + 0) * 128], a[0]);
        a[1] = fmaf(w4.y, ci[(c0 + 1) * 128], a[1]);
        a[2] = fmaf(w4.z, ci[(c0 + 2) * 128], a[2]);
        a[3] = fmaf(w4.w, ci[(c0 + 3) * 128], a[3]);
      }
      amat[(size_t)b * 16384 + g] = (a[0] + a[1]) + (a[2] + a[3]);
    } else {
      const int i = g - 16384;
      const int m = i >> 6, l = i & 63;
      const float* w = wb + m * 256;
      const float* ct = cintra + (size_t)b * 256 * 64 + l;
      float a[4] = {0.f, 0.f, 0.f, 0.f};
      for (int c0 = 0; c0 < 256; c0 += 4) {
        float4 w4 = *(const float4*)(w + c0);
        a[0] = fmaf(w4.x, ct[(c0 + 0) * 64], a[0]);
        a[1] = fmaf(w4.y, ct[(c0 + 1) * 64], a[1]);
        a[2] = fmaf(w4.z, ct[(c0 + 2) * 64], a[2]);
        a[3] = fmaf(w4.w, ct[(c0 + 3) * 64], a[3]);
      }
      bmat[(size_t)b * 8192 + i] = (a[0] + a[1]) + (a[2] + a[3]);
    }
  }
}

// ---------------------------------------------------------------------------
// K5: an[b,n,o] = sum_m wn[o,m]*a[b,m,n]   ; bl[b,l,o] = sum_m wl[o,m]*bm[b,m,l]
// grid 16*8, block 256
// ---------------------------------------------------------------------------
__global__ __launch_bounds__(256) void k_nl(const float* __restrict__ wn,
                                            const float* __restrict__ wl,
                                            const float* __restrict__ amat,
                                            const float* __restrict__ bmat,
                                            float* __restrict__ anmat,
                                            float* __restrict__ blmat) {
  const int blk = blockIdx.x;
  const int b = blk >> 3, part = blk & 7;
  const int tid = threadIdx.x;
  for (int k = 0; k < 12; ++k) {
    const int g = part * 3072 + k * 256 + tid;
    if (g < 16384) {
      const int n = g >> 7, o = g & 127;
      const float* w = wn + o * 128;
      const float* av = amat + (size_t)b * 16384 + n;   // a[m][n]: m*128+n
      float a[4] = {0.f, 0.f, 0.f, 0.f};
      for (int m0 = 0; m0 < 128; m0 += 4) {
        float4 w4 = *(const float4*)(w + m0);
        a[0] = fmaf(w4.x, av[(m0 + 0) * 128], a[0]);
        a[1] = fmaf(w4.y, av[(m0 + 1) * 128], a[1]);
        a[2] = fmaf(w4.z, av[(m0 + 2) * 128], a[2]);
        a[3] = fmaf(w4.w, av[(m0 + 3) * 128], a[3]);
      }
      anmat[(size_t)b * 16384 + g] = (a[0] + a[1]) + (a[2] + a[3]);  // [n][o]
    } else {
      const int i = g - 16384;
      const int l = i >> 7, o = i & 127;
      const float* w = wl + o * 128;
      const float* bv = bmat + (size_t)b * 8192 + l;    // bm[m][l]: m*64+l
      float a[4] = {0.f, 0.f, 0.f, 0.f};
      for (int m0 = 0; m0 < 128; m0 += 4) {
        float4 w4 = *(const float4*)(w + m0);
        a[0] = fmaf(w4.x, bv[(m0 + 0) * 64], a[0]);
        a[1] = fmaf(w4.y, bv[(m0 + 1) * 64], a[1]);
        a[2] = fmaf(w4.z, bv[(m0 + 2) * 64], a[2]);
        a[3] = fmaf(w4.w, bv[(m0 + 3) * 64], a[3]);
      }
      blmat[(size_t)b * 8192 + i] = (a[0] + a[1]) + (a[2] + a[3]);   // [l][o]
    }
  }
}

// ---------------------------------------------------------------------------
// K6 (fused): per 64-point tile:
//   logits = wc@x ; s_inter=softmax_n(aT@logits) ; xi = anT@s_inter
//   s_intra=softmax_l(bT@logits) ; xt = blT@s_intra
//   y = wd@[xi;xt] ; out = leaky(x + BN(y))
// grid 16*128, block 256, LDS = 64K + 32K + 32K + 512B
// ---------------------------------------------------------------------------
__global__ __launch_bounds__(256) void k_big(
    const float* __restrict__ x, const float* __restrict__ wc,
    const float* __restrict__ wd,
    const float* __restrict__ amat, const float* __restrict__ bmat,
    const float* __restrict__ anmat, const float* __restrict__ blmat,
    const float* __restrict__ bng, const float* __restrict__ bnb,
    const float* __restrict__ bnm, const float* __restrict__ bnv,
    float* __restrict__ out) {
  __shared__ float Xs[C_ * 64];     // x tile [c][p]
  __shared__ float Ls[MID_ * 64];   // logits [m][p] -> feat lo [xi]
  __shared__ float Ss[MID_ * 64];   // scores [n|l][p] -> feat hi [xt]
  __shared__ float red[128];        // [0:64) inter rcp, [64:128) intra rcp

  const int tid = threadIdx.x;
  const int blk = blockIdx.x;
  const int b = blk >> 7;
  const int p0 = (blk & 127) << 6;
  const int p = tid & 63;
  const int qu = __builtin_amdgcn_readfirstlane(tid >> 6);   // wave id 0..3

  // ---- stage x tile
  const float* xb = x + (size_t)b * C_ * N_ + p0;
  for (int i4 = tid; i4 < 4096; i4 += 256) {
    const int c = i4 >> 4, pq = (i4 & 15) * 4;
    *(float4*)&Xs[c * 64 + pq] = *(const float4*)&xb[(size_t)c * N_ + pq];
  }
  __syncthreads();

  // ---- logits[m][p], m = qu*32 + j
  for (int j0 = 0; j0 < 32; j0 += 4) {
    const int m0 = qu * 32 + j0;
    const float* w = wc + m0 * 256;
    float acc[4] = {0.f, 0.f, 0.f, 0.f};
    for (int c0 = 0; c0 < 256; c0 += 4) {
      const float x0 = Xs[(c0 + 0) * 64 + p];
      const float x1 = Xs[(c0 + 1) * 64 + p];
      const float x2 = Xs[(c0 + 2) * 64 + p];
      const float x3 = Xs[(c0 + 3) * 64 + p];
      #pragma unroll
      for (int k = 0; k < 4; ++k) {
        float4 w4 = *(const float4*)(w + k * 256 + c0);
        acc[k] = fmaf(w4.x, x0, acc[k]);
        acc[k] = fmaf(w4.y, x1, acc[k]);
        acc[k] = fmaf(w4.z, x2, acc[k]);
        acc[k] = fmaf(w4.w, x3, acc[k]);
      }
    }
    #pragma unroll
    for (int k = 0; k < 4; ++k) Ls[(m0 + k) * 64 + p] = acc[k];
  }
  __syncthreads();

  // ---- s_inter[n][p] = sum_m a[m][n]*logits[m][p]
  for (int j0 = 0; j0 < 32; j0 += 4) {
    const int n0 = qu * 32 + j0;
    const float* ab = amat + (size_t)b * 16384 + n0;
    float acc[4] = {0.f, 0.f, 0.f, 0.f};
    for (int m = 0; m < 128; ++m) {
      const float lv = Ls[m * 64 + p];
      float4 av = *(const float4*)(ab + m * 128);
      acc[0] = fmaf(av.x, lv, acc[0]);
      acc[1] = fmaf(av.y, lv, acc[1]);
      acc[2] = fmaf(av.z, lv, acc[2]);
      acc[3] = fmaf(av.w, lv, acc[3]);
    }
    #pragma unroll
    for (int k = 0; k < 4; ++k) Ss[(n0 + k) * 64 + p] = acc[k];
  }
  __syncthreads();

  // ---- softmax over n (128) per column p; leave exp() in Ss, rcp in red
  if (tid < 64) {
    float mx = -1e30f;
    for (int n = 0; n < 128; ++n) mx = fmaxf(mx, Ss[n * 64 + tid]);
    float s = 0.f;
    for (int n = 0; n < 128; ++n) {
      const float e = __expf(Ss[n * 64 + tid] - mx);
      Ss[n * 64 + tid] = e; s += e;
    }
    red[tid] = 1.f / s;
  }
  __syncthreads();

  // ---- xi[m][p] = (sum_n e[n][p]*an[n][m]) * rcp[p]   (kept in regs)
  float rxi[32];
  #pragma unroll
  for (int j0 = 0; j0 < 32; j0 += 4) {
    const int m0 = qu * 32 + j0;
    const float* anb = anmat + (size_t)b * 16384 + m0;
    float acc[4] = {0.f, 0.f, 0.f, 0.f};
    for (int n = 0; n < 128; ++n) {
      const float sv = Ss[n * 64 + p];
      float4 av = *(const float4*)(anb + n * 128);
      acc[0] = fmaf(av.x, sv, acc[0]);
      acc[1] = fmaf(av.y, sv, acc[1]);
      acc[2] = fmaf(av.z, sv, acc[2]);
      acc[3] = fmaf(av.w, sv, acc[3]);
    }
    const float r = red[p];
    #pragma unroll
    for (int k = 0; k < 4; ++k) rxi[j0 + k] = acc[k] * r;
  }
  __syncthreads();   // done reading Ss (inter exps)

  // ---- s_intra[l][p] = sum_m bm[m][l]*logits[m][p]  (l = qu*16 + j)
  for (int j0 = 0; j0 < 16; j0 += 4) {
    const int l0 = qu * 16 + j0;
    const float* bb = bmat + (size_t)b * 8192 + l0;
    float acc[4] = {0.f, 0.f, 0.f, 0.f};
    for (int m = 0; m < 128; ++m) {
      const float lv = Ls[m * 64 + p];
      float4 bv = *(const float4*)(bb + m * 64);
      acc[0] = fmaf(bv.x, lv, acc[0]);
      acc[1] = fmaf(bv.y, lv, acc[1]);
      acc[2] = fmaf(bv.z, lv, acc[2]);
      acc[3] = fmaf(bv.w, lv, acc[3]);
    }
    #pragma unroll
    for (int k = 0; k < 4; ++k) Ss[(l0 + k) * 64 + p] = acc[k];
  }
  __syncthreads();

  // ---- softmax over l (64) per column p
  if (tid < 64) {
    float mx = -1e30f;
    for (int l = 0; l < 64; ++l) mx = fmaxf(mx, Ss[l * 64 + tid]);
    float s = 0.f;
    for (int l = 0; l < 64; ++l) {
      const float e = __expf(Ss[l * 64 + tid] - mx);
      Ss[l * 64 + tid] = e; s += e;
    }
    red[64 + tid] = 1.f / s;
  }
  __syncthreads();

  // ---- xt[m][p] = (sum_l e[l][p]*bl[l][m]) * rcp2[p]
  float rxt[32];
  #pragma unroll
  for (int j0 = 0; j0 < 32; j0 += 4) {
    const int m0 = qu * 32 + j0;
    const float* blb = blmat + (size_t)b * 8192 + m0;
    float acc[4] = {0.f, 0.f, 0.f, 0.f};
    for (int l = 0; l < 64; ++l) {
      const float sv = Ss[l * 64 + p];
      float4 bv = *(const float4*)(blb + l * 128);
      acc[0] = fmaf(bv.x, sv, acc[0]);
      acc[1] = fmaf(bv.y, sv, acc[1]);
      acc[2] = fmaf(bv.z, sv, acc[2]);
      acc[3] = fmaf(bv.w, sv, acc[3]);
    }
    const float r = red[64 + p];
    #pragma unroll
    for (int k = 0; k < 4; ++k) rxt[j0 + k] = acc[k] * r;
  }
  __syncthreads();   // done reading Ls (logits) and Ss (intra exps)

  // ---- write feat: lo -> Ls, hi -> Ss
  #pragma unroll
  for (int j = 0; j < 32; ++j) {
    Ls[(qu * 32 + j) * 64 + p] = rxi[j];
    Ss[(qu * 32 + j) * 64 + p] = rxt[j];
  }
  __syncthreads();

  // ---- y[c][p] = sum_d wd[c][d]*feat[d][p]; BN + residual + leaky
  for (int jj0 = 0; jj0 < 64; jj0 += 4) {
    const int c0 = qu * 64 + jj0;
    const float* w0 = wd + c0 * 256;
    float acc[4] = {0.f, 0.f, 0.f, 0.f};
    for (int d0 = 0; d0 < 128; d0 += 4) {
      const float f0 = Ls[(d0 + 0) * 64 + p];
      const float f1 = Ls[(d0 + 1) * 64 + p];
      const float f2 = Ls[(d0 + 2) * 64 + p];
      const float f3 = Ls[(d0 + 3) * 64 + p];
      #pragma unroll
      for (int k = 0; k < 4; ++k) {
        float4 w4 = *(const float4*)(w0 + k * 256 + d0);
        acc[k] = fmaf(w4.x, f0, acc[k]);
        acc[k] = fmaf(w4.y, f1, acc[k]);
        acc[k] = fmaf(w4.z, f2, acc[k]);
        acc[k] = fmaf(w4.w, f3, acc[k]);
      }
    }
    for (int d0 = 0; d0 < 128; d0 += 4) {
      const float f0 = Ss[(d0 + 0) * 64 + p];
      const float f1 = Ss[(d0 + 1) * 64 + p];
      const float f2 = Ss[(d0 + 2) * 64 + p];
      const float f3 = Ss[(d0 + 3) * 64 + p];
      #pragma unroll
      for (int k = 0; k < 4; ++k) {
        float4 w4 = *(const float4*)(w0 + k * 256 + 128 + d0);
        acc[k] = fmaf(w4.x, f0, acc[k]);
        acc[k] = fmaf(w4.y, f1, acc[k]);
        acc[k] = fmaf(w4.z, f2, acc[k]);
        acc[k] = fmaf(w4.w, f3, acc[k]);
      }
    }
    #pragma unroll
    for (int k = 0; k < 4; ++k) {
      const int c = c0 + k;
      const float sc = bng[c] * rsqrtf(bnv[c] + 1e-5f);
      const float yv = (acc[k] - bnm[c]) * sc + bnb[c];
      const float z = Xs[c * 64 + p] + yv;
      out[((size_t)b * C_ + c) * N_ + p0 + p] = z > 0.f ? z : 0.2f * z;
    }
  }
}

// ---------------------------------------------------------------------------
extern "C" void kernel_launch(void* const* d_in, const int* in_sizes, int n_in,
                              void* d_out, int out_size, void* d_ws, size_t ws_size,
                              hipStream_t stream) {
  const float* x      = (const float*)d_in[0];
  const float* curves = (const float*)d_in[1];
  const float* w_att  = (const float*)d_in[2];
  const float* wa     = (const float*)d_in[3];
  const float* wb     = (const float*)d_in[4];
  const float* wc     = (const float*)d_in[5];
  const float* wn     = (const float*)d_in[6];
  const float* wl     = (const float*)d_in[7];
  const float* wd     = (const float*)d_in[8];
  const float* bng    = (const float*)d_in[9];
  const float* bnb    = (const float*)d_in[10];
  const float* bnm    = (const float*)d_in[11];
  const float* bnv    = (const float*)d_in[12];
  float* out = (float*)d_out;
  float* ws  = (float*)d_ws;

  float* att    = ws;                 // 131072
  float* smi    = ws + 131072;        // 131072
  float* sma    = ws + 262144;        // 131072
  float* cinter = ws + 393216;        // 524288
  float* cintra = ws + 917504;        // 262144
  float* amat   = ws + 1179648;       // 262144
  float* bmat   = ws + 1441792;       // 131072
  float* anmat  = ws + 1572864;       // 262144
  float* blmat  = ws + 1835008;       // 131072  (end = 1966080 floats = 7.5 MiB)

  k_att    <<<dim3(B_ * 32),  dim3(256), 0, stream>>>(curves, w_att, att);
  k_softmax<<<dim3(B_),       dim3(256), 0, stream>>>(att, smi, sma);
  k_agg    <<<dim3(B_ * C_),  dim3(256), 0, stream>>>(curves, smi, sma, cinter, cintra);
  k_ab     <<<dim3(B_ * 8),   dim3(256), 0, stream>>>(wa, wb, cinter, cintra, amat, bmat);
  k_nl     <<<dim3(B_ * 8),   dim3(256), 0, stream>>>(wn, wl, amat, bmat, anmat, blmat);
  k_big    <<<dim3(B_ * 128), dim3(256), 0, stream>>>(x, wc, wd, amat, bmat, anmat, blmat,
                                                      bng, bnb, bnm, bnv, out);
}

// Round 2
// 623.082 us; speedup vs baseline: 13.7709x; 13.7709x over previous
//
#include <hip/hip_runtime.h>
#include <hip/hip_bf16.h>
#include <cstdint>

#define B_   16
#define C_   256
#define N_   8192
#define CN_  128
#define CL_  64
#define MID_ 128

typedef unsigned short u16;
typedef __attribute__((ext_vector_type(8))) short bf8;
typedef __attribute__((ext_vector_type(4))) float f4;

#define MFMA(a, bb, c) __builtin_amdgcn_mfma_f32_16x16x32_bf16(a, bb, c, 0, 0, 0)

__device__ inline u16 f2b(float v) {
  uint32_t b = __builtin_bit_cast(uint32_t, v);
  uint32_t r = (b + 0x7FFFu + ((b >> 16) & 1u)) >> 16;
  return (u16)r;
}
__device__ inline float b2f(u16 u) {
  uint32_t b = ((uint32_t)u) << 16;
  return __builtin_bit_cast(float, b);
}
__device__ inline void st4(u16* p, u16 a, u16 b, u16 c, u16 d) {
  unsigned long long v = (unsigned long long)a | ((unsigned long long)b << 16) |
                         ((unsigned long long)c << 32) | ((unsigned long long)d << 48);
  *(unsigned long long*)p = v;
}

// ---------------------------------------------------------------------------
// K1: att[b,n,l] = sum_c w_att[c] * curves[b,c,n,l]
// ---------------------------------------------------------------------------
__global__ __launch_bounds__(256) void k_att(const float* __restrict__ curves,
                                             const float* __restrict__ w_att,
                                             float* __restrict__ att) {
  const int blk = blockIdx.x;
  const int b = blk >> 5, nc = blk & 31;
  const int tid = threadIdx.x;
  const float* cb = curves + (size_t)b * C_ * CN_ * CL_ + nc * 256 + tid;
  float a0 = 0.f, a1 = 0.f, a2 = 0.f, a3 = 0.f;
  for (int c0 = 0; c0 < C_; c0 += 4) {
    a0 = fmaf(w_att[c0 + 0], cb[(size_t)(c0 + 0) * 8192], a0);
    a1 = fmaf(w_att[c0 + 1], cb[(size_t)(c0 + 1) * 8192], a1);
    a2 = fmaf(w_att[c0 + 2], cb[(size_t)(c0 + 2) * 8192], a2);
    a3 = fmaf(w_att[c0 + 3], cb[(size_t)(c0 + 3) * 8192], a3);
  }
  att[b * 8192 + nc * 256 + tid] = (a0 + a1) + (a2 + a3);
}

// ---------------------------------------------------------------------------
// K2: dual softmax of att
// ---------------------------------------------------------------------------
__global__ __launch_bounds__(256) void k_softmax(const float* __restrict__ att,
                                                 float* __restrict__ smi,
                                                 float* __restrict__ sma) {
  __shared__ float T[CN_ * CL_];
  __shared__ float rmax[CN_], rrcp[CN_], cmax[CL_], crcp[CL_];
  const int b = blockIdx.x;
  const int tid = threadIdx.x;
  for (int idx = tid; idx < CN_ * CL_; idx += 256) T[idx] = att[b * 8192 + idx];
  __syncthreads();
  if (tid < 128) {
    const int n = tid;
    float mx = -1e30f;
    for (int l = 0; l < CL_; ++l) mx = fmaxf(mx, T[n * 64 + l]);
    float s = 0.f;
    for (int l = 0; l < CL_; ++l) s += __expf(T[n * 64 + l] - mx);
    rmax[n] = mx; rrcp[n] = 1.f / s;
  } else if (tid < 192) {
    const int l = tid - 128;
    float mx = -1e30f;
    for (int n = 0; n < CN_; ++n) mx = fmaxf(mx, T[n * 64 + l]);
    float s = 0.f;
    for (int n = 0; n < CN_; ++n) s += __expf(T[n * 64 + l] - mx);
    cmax[l] = mx; crcp[l] = 1.f / s;
  }
  __syncthreads();
  for (int idx = tid; idx < CN_ * CL_; idx += 256) {
    const int n = idx >> 6, l = idx & 63;
    const float v = T[idx];
    smi[b * 8192 + idx] = __expf(v - rmax[n]) * rrcp[n];
    sma[b * 8192 + idx] = __expf(v - cmax[l]) * crcp[l];
  }
}

// ---------------------------------------------------------------------------
// K3: curve aggregation
// ---------------------------------------------------------------------------
__global__ __launch_bounds__(256) void k_agg(const float* __restrict__ curves,
                                             const float* __restrict__ smi,
                                             const float* __restrict__ sma,
                                             float* __restrict__ cinter,
                                             float* __restrict__ cintra) {
  __shared__ float P[CN_ * CL_];
  const int blk = blockIdx.x;
  const int b = blk >> 8, c = blk & 255;
  const int tid = threadIdx.x;
  const float* src = curves + (size_t)(b * 256 + c) * 8192;
  for (int i4 = tid; i4 < 2048; i4 += 256)
    *(float4*)&P[i4 * 4] = *(const float4*)&src[i4 * 4];
  __syncthreads();
  if (tid < 128) {
    const int n = tid;
    const float* sp = smi + (size_t)(b * 128 + n) * 64;
    float a[4] = {0.f, 0.f, 0.f, 0.f};
    for (int l0 = 0; l0 < 64; l0 += 4) {
      float4 pv = *(const float4*)&P[n * 64 + l0];
      float4 sv = *(const float4*)&sp[l0];
      a[0] = fmaf(pv.x, sv.x, a[0]);
      a[1] = fmaf(pv.y, sv.y, a[1]);
      a[2] = fmaf(pv.z, sv.z, a[2]);
      a[3] = fmaf(pv.w, sv.w, a[3]);
    }
    cinter[(size_t)(b * 256 + c) * 128 + n] = (a[0] + a[1]) + (a[2] + a[3]);
  } else if (tid < 192) {
    const int l = tid - 128;
    float a[4] = {0.f, 0.f, 0.f, 0.f};
    for (int n0 = 0; n0 < 128; n0 += 4) {
      a[0] = fmaf(P[(n0 + 0) * 64 + l], sma[(size_t)(b * 128 + n0 + 0) * 64 + l], a[0]);
      a[1] = fmaf(P[(n0 + 1) * 64 + l], sma[(size_t)(b * 128 + n0 + 1) * 64 + l], a[1]);
      a[2] = fmaf(P[(n0 + 2) * 64 + l], sma[(size_t)(b * 128 + n0 + 2) * 64 + l], a[2]);
      a[3] = fmaf(P[(n0 + 3) * 64 + l], sma[(size_t)(b * 128 + n0 + 3) * 64 + l], a[3]);
    }
    cintra[(size_t)(b * 256 + c) * 64 + l] = (a[0] + a[1]) + (a[2] + a[3]);
  }
}

// ---------------------------------------------------------------------------
// K4: a = wa@cinter ; bm = wb@cintra
// ---------------------------------------------------------------------------
__global__ __launch_bounds__(256) void k_ab(const float* __restrict__ wa,
                                            const float* __restrict__ wb,
                                            const float* __restrict__ cinter,
                                            const float* __restrict__ cintra,
                                            float* __restrict__ amat,
                                            float* __restrict__ bmat) {
  const int blk = blockIdx.x;
  const int b = blk >> 3, part = blk & 7;
  const int tid = threadIdx.x;
  for (int k = 0; k < 12; ++k) {
    const int g = part * 3072 + k * 256 + tid;
    if (g < 16384) {
      const int m = g >> 7, n = g & 127;
      const float* w = wa + m * 256;
      const float* ci = cinter + (size_t)b * 256 * 128 + n;
      float a[4] = {0.f, 0.f, 0.f, 0.f};
      for (int c0 = 0; c0 < 256; c0 += 4) {
        float4 w4 = *(const float4*)(w + c0);
        a[0] = fmaf(w4.x, ci[(c0 + 0) * 128], a[0]);
        a[1] = fmaf(w4.y, ci[(c0 + 1) * 128], a[1]);
        a[2] = fmaf(w4.z, ci[(c0 + 2) * 128], a[2]);
        a[3] = fmaf(w4.w, ci[(c0 + 3) * 128], a[3]);
      }
      amat[(size_t)b * 16384 + g] = (a[0] + a[1]) + (a[2] + a[3]);
    } else {
      const int i = g - 16384;
      const int m = i >> 6, l = i & 63;
      const float* w = wb + m * 256;
      const float* ct = cintra + (size_t)b * 256 * 64 + l;
      float a[4] = {0.f, 0.f, 0.f, 0.f};
      for (int c0 = 0; c0 < 256; c0 += 4) {
        float4 w4 = *(const float4*)(w + c0);
        a[0] = fmaf(w4.x, ct[(c0 + 0) * 64], a[0]);
        a[1] = fmaf(w4.y, ct[(c0 + 1) * 64], a[1]);
        a[2] = fmaf(w4.z, ct[(c0 + 2) * 64], a[2]);
        a[3] = fmaf(w4.w, ct[(c0 + 3) * 64], a[3]);
      }
      bmat[(size_t)b * 8192 + i] = (a[0] + a[1]) + (a[2] + a[3]);
    }
  }
}

// ---------------------------------------------------------------------------
// K5: an = wn@a (as [n][o]) ; bl = wl@bm (as [l][o])
// ---------------------------------------------------------------------------
__global__ __launch_bounds__(256) void k_nl(const float* __restrict__ wn,
                                            const float* __restrict__ wl,
                                            const float* __restrict__ amat,
                                            const float* __restrict__ bmat,
                                            float* __restrict__ anmat,
                                            float* __restrict__ blmat) {
  const int blk = blockIdx.x;
  const int b = blk >> 3, part = blk & 7;
  const int tid = threadIdx.x;
  for (int k = 0; k < 12; ++k) {
    const int g = part * 3072 + k * 256 + tid;
    if (g < 16384) {
      const int n = g >> 7, o = g & 127;
      const float* w = wn + o * 128;
      const float* av = amat + (size_t)b * 16384 + n;
      float a[4] = {0.f, 0.f, 0.f, 0.f};
      for (int m0 = 0; m0 < 128; m0 += 4) {
        float4 w4 = *(const float4*)(w + m0);
        a[0] = fmaf(w4.x, av[(m0 + 0) * 128], a[0]);
        a[1] = fmaf(w4.y, av[(m0 + 1) * 128], a[1]);
        a[2] = fmaf(w4.z, av[(m0 + 2) * 128], a[2]);
        a[3] = fmaf(w4.w, av[(m0 + 3) * 128], a[3]);
      }
      anmat[(size_t)b * 16384 + g] = (a[0] + a[1]) + (a[2] + a[3]);
    } else {
      const int i = g - 16384;
      const int l = i >> 7, o = i & 127;
      const float* w = wl + o * 128;
      const float* bv = bmat + (size_t)b * 8192 + l;
      float a[4] = {0.f, 0.f, 0.f, 0.f};
      for (int m0 = 0; m0 < 128; m0 += 4) {
        float4 w4 = *(const float4*)(w + m0);
        a[0] = fmaf(w4.x, bv[(m0 + 0) * 64], a[0]);
        a[1] = fmaf(w4.y, bv[(m0 + 1) * 64], a[1]);
        a[2] = fmaf(w4.z, bv[(m0 + 2) * 64], a[2]);
        a[3] = fmaf(w4.w, bv[(m0 + 3) * 64], a[3]);
      }
      blmat[(size_t)b * 8192 + i] = (a[0] + a[1]) + (a[2] + a[3]);
    }
  }
}

// ---------------------------------------------------------------------------
// K6: prep — bf16 (hi/lo where needed) transposed copies of all GEMM operands
// ---------------------------------------------------------------------------
__global__ __launch_bounds__(256) void k_prep(
    const float* __restrict__ wc, const float* __restrict__ wd,
    const float* __restrict__ amat, const float* __restrict__ bmat,
    const float* __restrict__ anmat, const float* __restrict__ blmat,
    u16* __restrict__ wcH, u16* __restrict__ wcL, u16* __restrict__ wdB,
    u16* __restrict__ aTH, u16* __restrict__ aTL,
    u16* __restrict__ bTH, u16* __restrict__ bTL,
    u16* __restrict__ anT, u16* __restrict__ blT) {
  const int i = blockIdx.x * 256 + threadIdx.x;
  if (i < 32768) {
    float v = wc[i]; u16 h = f2b(v); wcH[i] = h; wcL[i] = f2b(v - b2f(h));
  } else if (i < 98304) {
    const int q = i - 32768; wdB[q] = f2b(wd[q]);
  } else if (i < 360448) {
    const int j = i - 98304;
    const int bb = j >> 14, r = j & 16383, n = r >> 7, m = r & 127;
    float v = amat[(size_t)bb * 16384 + m * 128 + n];
    u16 h = f2b(v); aTH[j] = h; aTL[j] = f2b(v - b2f(h));
  } else if (i < 491520) {
    const int j = i - 360448;
    const int bb = j >> 13, r = j & 8191, l = r >> 7, m = r & 127;
    float v = bmat[(size_t)bb * 8192 + m * 64 + l];
    u16 h = f2b(v); bTH[j] = h; bTL[j] = f2b(v - b2f(h));
  } else if (i < 753664) {
    const int j = i - 491520;
    const int bb = j >> 14, r = j & 16383, m = r >> 7, n = r & 127;
    anT[j] = f2b(anmat[(size_t)bb * 16384 + n * 128 + m]);
  } else if (i < 884736) {
    const int j = i - 753664;
    const int bb = j >> 13, r = j & 8191, m = r >> 6, l = r & 63;
    blT[j] = f2b(blmat[(size_t)bb * 8192 + l * 128 + m]);
  }
}

// ---------------------------------------------------------------------------
// K7 (fused MFMA): per 64-point tile, 4 waves x 16-col strips.
// Stages 1/2/5 (softmax-logit chain) use hi/lo bf16 split (3 MFMAs) for
// ~f32 accuracy; stages 4/7/8 plain bf16. LDS = exactly 80 KB -> 2 blk/CU.
// ---------------------------------------------------------------------------
__global__ __launch_bounds__(256, 2) void k_big(
    const float* __restrict__ x,
    const u16* __restrict__ wcH, const u16* __restrict__ wcL,
    const u16* __restrict__ wdB,
    const u16* __restrict__ aTH, const u16* __restrict__ aTL,
    const u16* __restrict__ bTH, const u16* __restrict__ bTL,
    const u16* __restrict__ anT, const u16* __restrict__ blT,
    const float* __restrict__ bng, const float* __restrict__ bnb,
    const float* __restrict__ bnm, const float* __restrict__ bnv,
    float* __restrict__ out) {
  __shared__ __align__(16) u16 LDS[40960];          // 80 KB total
  u16* XtH = LDS;               // [64][128] bf16 hi  (X^T half, swizzled)
  u16* XtL = LDS + 8192;        // [64][128] bf16 lo
  u16* FT  = LDS;               // [64][256] feat^T (reuses Xt region)
  u16* LTH = LDS + 16384;       // [64][128] logits^T hi
  u16* LTL = LDS + 24576;       // [64][128] logits^T lo
  u16* ET  = LDS + 32768;       // [64][128] exp^T (inter), then exp^T (intra)
  float* scL = (float*)(LDS + 16384);  // 256 f32 (aliases dead LTH)
  float* biL = (float*)(LDS + 16896);  // 256 f32

  const int tid  = threadIdx.x;
  const int lane = tid & 63;
  const int wid  = tid >> 6;
  const int l15  = lane & 15;
  const int lg   = lane >> 4;
  const int prow = wid * 16 + l15;       // this lane's p-row (0..63)
  const int kf   = lg * 8;               // frag k offset
  const int rsw  = (prow & 7) << 3;      // XOR swizzle for this row
  const int blk  = blockIdx.x;
  const int b    = blk >> 7;
  const int p0   = (blk & 127) << 6;

  const f4 zero4 = {0.f, 0.f, 0.f, 0.f};

  // ---------------- stage 1: L = wc @ X  (hi/lo, K split in 2 halves)
  f4 accL[8];
  #pragma unroll
  for (int t = 0; t < 8; ++t) accL[t] = zero4;

  const float* xb = x + (size_t)b * C_ * N_ + p0;
  for (int half = 0; half < 2; ++half) {
    __syncthreads();
    for (int i = tid; i < 2048; i += 256) {
      const int cc0 = (i >> 6) << 2, pp = i & 63;
      const size_t src = (size_t)(half * 128 + cc0) * N_ + pp;
      const float v0 = xb[src], v1 = xb[src + N_], v2 = xb[src + 2 * N_], v3 = xb[src + 3 * N_];
      const u16 h0 = f2b(v0), h1 = f2b(v1), h2 = f2b(v2), h3 = f2b(v3);
      const u16 g0 = f2b(v0 - b2f(h0)), g1 = f2b(v1 - b2f(h1));
      const u16 g2 = f2b(v2 - b2f(h2)), g3 = f2b(v3 - b2f(h3));
      const int idx = pp * 128 + (cc0 ^ ((pp & 7) << 3));
      st4(XtH + idx, h0, h1, h2, h3);
      st4(XtL + idx, g0, g1, g2, g3);
    }
    __syncthreads();
    #pragma unroll
    for (int ks = 0; ks < 4; ++ks) {
      const int kk = ks * 32 + kf;
      const bf8 bh = *(const bf8*)(XtH + prow * 128 + (kk ^ rsw));
      const bf8 bl = *(const bf8*)(XtL + prow * 128 + (kk ^ rsw));
      const int kg = half * 128 + kk;
      #pragma unroll
      for (int t = 0; t < 8; ++t) {
        const int ro = (t * 16 + l15) * 256 + kg;
        const bf8 ah = *(const bf8*)(wcH + ro);
        const bf8 al = *(const bf8*)(wcL + ro);
        accL[t] = MFMA(ah, bh, accL[t]);
        accL[t] = MFMA(ah, bl, accL[t]);
        accL[t] = MFMA(al, bh, accL[t]);
      }
    }
  }
  // write logits^T (hi/lo) — wave-private rows
  #pragma unroll
  for (int t = 0; t < 8; ++t) {
    const int m0 = t * 16 + lg * 4;
    const int idx = prow * 128 + (m0 ^ rsw);
    u16 h[4], g[4];
    #pragma unroll
    for (int r = 0; r < 4; ++r) {
      const float v = accL[t][r];
      h[r] = f2b(v); g[r] = f2b(v - b2f(h[r]));
    }
    st4(LTH + idx, h[0], h[1], h[2], h[3]);
    st4(LTL + idx, g[0], g[1], g[2], g[3]);
  }

  // ---------------- stage 2: SI = aT @ L (hi/lo) + softmax over n
  f4 accS[8];
  #pragma unroll
  for (int t = 0; t < 8; ++t) accS[t] = zero4;
  const u16* aHb = aTH + ((size_t)b << 14);
  const u16* aLb = aTL + ((size_t)b << 14);
  #pragma unroll
  for (int ks = 0; ks < 4; ++ks) {
    const int kk = ks * 32 + kf;
    const bf8 bh = *(const bf8*)(LTH + prow * 128 + (kk ^ rsw));
    const bf8 bl = *(const bf8*)(LTL + prow * 128 + (kk ^ rsw));
    #pragma unroll
    for (int t = 0; t < 8; ++t) {
      const int ro = (t * 16 + l15) * 128 + kk;
      const bf8 ah = *(const bf8*)(aHb + ro);
      const bf8 al = *(const bf8*)(aLb + ro);
      accS[t] = MFMA(ah, bh, accS[t]);
      accS[t] = MFMA(ah, bl, accS[t]);
      accS[t] = MFMA(al, bh, accS[t]);
    }
  }
  float mx = -3.0e38f;
  #pragma unroll
  for (int t = 0; t < 8; ++t)
    #pragma unroll
    for (int r = 0; r < 4; ++r) mx = fmaxf(mx, accS[t][r]);
  mx = fmaxf(mx, __shfl_xor(mx, 16));
  mx = fmaxf(mx, __shfl_xor(mx, 32));
  float sum = 0.f;
  #pragma unroll
  for (int t = 0; t < 8; ++t)
    #pragma unroll
    for (int r = 0; r < 4; ++r) {
      const float e = __expf(accS[t][r] - mx);
      accS[t][r] = e; sum += e;
    }
  sum += __shfl_xor(sum, 16);
  sum += __shfl_xor(sum, 32);
  const float rcpI = 1.f / sum;
  #pragma unroll
  for (int t = 0; t < 8; ++t) {
    const int idx = prow * 128 + ((t * 16 + lg * 4) ^ rsw);
    st4(ET + idx, f2b(accS[t][0]), f2b(accS[t][1]), f2b(accS[t][2]), f2b(accS[t][3]));
  }

  __syncthreads();   // all waves past stage-1 Xt reads -> FT region reusable

  // ---------------- stage 4: XI = anT @ E, scale by rcpI -> FT[:,0:128]
  f4 accX[8];
  #pragma unroll
  for (int t = 0; t < 8; ++t) accX[t] = zero4;
  const u16* anb = anT + ((size_t)b << 14);
  #pragma unroll
  for (int ks = 0; ks < 4; ++ks) {
    const int kk = ks * 32 + kf;
    const bf8 be = *(const bf8*)(ET + prow * 128 + (kk ^ rsw));
    #pragma unroll
    for (int t = 0; t < 8; ++t) {
      const bf8 a = *(const bf8*)(anb + (t * 16 + l15) * 128 + kk);
      accX[t] = MFMA(a, be, accX[t]);
    }
  }
  #pragma unroll
  for (int t = 0; t < 8; ++t) {
    const int idx = prow * 256 + ((t * 16 + lg * 4) ^ rsw);
    st4(FT + idx, f2b(accX[t][0] * rcpI), f2b(accX[t][1] * rcpI),
                  f2b(accX[t][2] * rcpI), f2b(accX[t][3] * rcpI));
  }

  // ---------------- stage 5: SA = bT @ L (hi/lo) + softmax over l
  f4 accA[4];
  #pragma unroll
  for (int t = 0; t < 4; ++t) accA[t] = zero4;
  const u16* bHb = bTH + ((size_t)b << 13);
  const u16* bLb = bTL + ((size_t)b << 13);
  #pragma unroll
  for (int ks = 0; ks < 4; ++ks) {
    const int kk = ks * 32 + kf;
    const bf8 bh = *(const bf8*)(LTH + prow * 128 + (kk ^ rsw));
    const bf8 bl = *(const bf8*)(LTL + prow * 128 + (kk ^ rsw));
    #pragma unroll
    for (int t = 0; t < 4; ++t) {
      const int ro = (t * 16 + l15) * 128 + kk;
      const bf8 ah = *(const bf8*)(bHb + ro);
      const bf8 al = *(const bf8*)(bLb + ro);
      accA[t] = MFMA(ah, bh, accA[t]);
      accA[t] = MFMA(ah, bl, accA[t]);
      accA[t] = MFMA(al, bh, accA[t]);
    }
  }
  float mx2 = -3.0e38f;
  #pragma unroll
  for (int t = 0; t < 4; ++t)
    #pragma unroll
    for (int r = 0; r < 4; ++r) mx2 = fmaxf(mx2, accA[t][r]);
  mx2 = fmaxf(mx2, __shfl_xor(mx2, 16));
  mx2 = fmaxf(mx2, __shfl_xor(mx2, 32));
  float sum2 = 0.f;
  #pragma unroll
  for (int t = 0; t < 4; ++t)
    #pragma unroll
    for (int r = 0; r < 4; ++r) {
      const float e = __expf(accA[t][r] - mx2);
      accA[t][r] = e; sum2 += e;
    }
  sum2 += __shfl_xor(sum2, 16);
  sum2 += __shfl_xor(sum2, 32);
  const float rcpT = 1.f / sum2;
  #pragma unroll
  for (int t = 0; t < 4; ++t) {   // E2^T into ET region, pitch 128 (wave-private rows)
    const int idx = prow * 128 + ((t * 16 + lg * 4) ^ rsw);
    st4(ET + idx, f2b(accA[t][0]), f2b(accA[t][1]), f2b(accA[t][2]), f2b(accA[t][3]));
  }

  __syncthreads();   // all waves done with LT -> scL/biL region writable
  {
    const float scv = bng[tid] * rsqrtf(bnv[tid] + 1e-5f);
    scL[tid] = scv;
    biL[tid] = bnb[tid] - bnm[tid] * scv;
  }

  // ---------------- stage 7: XT = blT @ E2, scale by rcpT -> FT[:,128:256]
  f4 accT[8];
  #pragma unroll
  for (int t = 0; t < 8; ++t) accT[t] = zero4;
  const u16* blb = blT + ((size_t)b << 13);
  #pragma unroll
  for (int ks = 0; ks < 2; ++ks) {
    const int kk = ks * 32 + kf;
    const bf8 be = *(const bf8*)(ET + prow * 128 + (kk ^ rsw));
    #pragma unroll
    for (int t = 0; t < 8; ++t) {
      const bf8 a = *(const bf8*)(blb + (t * 16 + l15) * 64 + kk);
      accT[t] = MFMA(a, be, accT[t]);
    }
  }
  #pragma unroll
  for (int t = 0; t < 8; ++t) {
    const int idx = prow * 256 + ((128 + t * 16 + lg * 4) ^ rsw);
    st4(FT + idx, f2b(accT[t][0] * rcpT), f2b(accT[t][1] * rcpT),
                  f2b(accT[t][2] * rcpT), f2b(accT[t][3] * rcpT));
  }

  __syncthreads();   // scL/biL visible

  // ---------------- stage 8: Y = wd @ F ; BN + residual + leaky
  f4 acc8[16];
  #pragma unroll
  for (int t = 0; t < 16; ++t) acc8[t] = zero4;
  #pragma unroll
  for (int ks = 0; ks < 8; ++ks) {
    const int kk = ks * 32 + kf;
    const bf8 bfr = *(const bf8*)(FT + prow * 256 + (kk ^ rsw));
    #pragma unroll
    for (int t = 0; t < 16; ++t) {
      const bf8 a = *(const bf8*)(wdB + (t * 16 + l15) * 256 + kk);
      acc8[t] = MFMA(a, bfr, acc8[t]);
    }
  }
  const size_t pcol = (size_t)p0 + wid * 16 + l15;
  #pragma unroll
  for (int t = 0; t < 16; ++t) {
    #pragma unroll
    for (int r = 0; r < 4; ++r) {
      const int c = t * 16 + lg * 4 + r;
      const size_t o = (((size_t)b * 256 + c) << 13) + pcol;
      const float z = x[o] + acc8[t][r] * scL[c] + biL[c];
      out[o] = z > 0.f ? z : 0.2f * z;
    }
  }
}

// ---------------------------------------------------------------------------
extern "C" void kernel_launch(void* const* d_in, const int* in_sizes, int n_in,
                              void* d_out, int out_size, void* d_ws, size_t ws_size,
                              hipStream_t stream) {
  const float* x      = (const float*)d_in[0];
  const float* curves = (const float*)d_in[1];
  const float* w_att  = (const float*)d_in[2];
  const float* wa     = (const float*)d_in[3];
  const float* wb     = (const float*)d_in[4];
  const float* wc     = (const float*)d_in[5];
  const float* wn     = (const float*)d_in[6];
  const float* wl     = (const float*)d_in[7];
  const float* wd     = (const float*)d_in[8];
  const float* bng    = (const float*)d_in[9];
  const float* bnb    = (const float*)d_in[10];
  const float* bnm    = (const float*)d_in[11];
  const float* bnv    = (const float*)d_in[12];
  float* out = (float*)d_out;
  float* ws  = (float*)d_ws;

  // f32 scratch (upper region)
  float* att    = ws;                 // dead after k_softmax
  float* smi    = ws + 131072;
  float* sma    = ws + 262144;
  float* cinter = ws + 393216;        // dead after k_ab
  float* cintra = ws + 917504;
  float* amat   = ws + 1179648;
  float* bmat   = ws + 1441792;
  float* anmat  = ws + 1572864;
  float* blmat  = ws + 1835008;       // end 1966080 f32 (7.5 MiB)

  // bf16 prep outputs (reuse lower region, dead by the time k_prep runs)
  u16* wsb  = (u16*)d_ws;
  u16* wcH  = wsb;                    // 32768
  u16* wcL  = wsb + 32768;
  u16* wdB  = wsb + 65536;            // 65536
  u16* aTHp = wsb + 131072;           // 262144
  u16* aTLp = wsb + 393216;
  u16* bTHp = wsb + 655360;           // 131072
  u16* bTLp = wsb + 786432;
  u16* anTp = wsb + 917504;           // 262144
  u16* blTp = wsb + 1179648;          // 131072 -> end 1310720 u16 (< 1179648 f32)

  k_att    <<<dim3(B_ * 32),  dim3(256), 0, stream>>>(curves, w_att, att);
  k_softmax<<<dim3(B_),       dim3(256), 0, stream>>>(att, smi, sma);
  k_agg    <<<dim3(B_ * C_),  dim3(256), 0, stream>>>(curves, smi, sma, cinter, cintra);
  k_ab     <<<dim3(B_ * 8),   dim3(256), 0, stream>>>(wa, wb, cinter, cintra, amat, bmat);
  k_nl     <<<dim3(B_ * 8),   dim3(256), 0, stream>>>(wn, wl, amat, bmat, anmat, blmat);
  k_prep   <<<dim3(3456),     dim3(256), 0, stream>>>(wc, wd, amat, bmat, anmat, blmat,
                                                      wcH, wcL, wdB, aTHp, aTLp,
                                                      bTHp, bTLp, anTp, blTp);
  k_big    <<<dim3(B_ * 128), dim3(256), 0, stream>>>(x, wcH, wcL, wdB, aTHp, aTLp,
                                                      bTHp, bTLp, anTp, blTp,
                                                      bng, bnb, bnm, bnv, out);
}